// Round 1
// baseline (1321.718 us; speedup 1.0000x reference)
//
#include <hip/hip_runtime.h>

#define BS 256

// ---------------- CSR build ----------------

__global__ __launch_bounds__(BS) void k_zero2(int* a, int* b, int n) {
    int i = blockIdx.x * BS + threadIdx.x;
    if (i < n) { a[i] = 0; b[i] = 0; }
}

__global__ __launch_bounds__(BS) void k_hist(const int* __restrict__ dst, int* __restrict__ cnt, int E) {
    int e = blockIdx.x * BS + threadIdx.x;
    if (e < E) atomicAdd(&cnt[dst[e]], 1);
}

__global__ __launch_bounds__(BS) void k_dinv(const int* __restrict__ cnt, float* __restrict__ dinv, int N) {
    int i = blockIdx.x * BS + threadIdx.x;
    if (i < N) dinv[i] = rsqrtf((float)(cnt[i] + 1));   // +1 = self-loop
}

__global__ __launch_bounds__(BS) void k_scan1(const int* __restrict__ cnt, int* __restrict__ bsum, int N) {
    __shared__ int s[BS];
    int i = blockIdx.x * BS + threadIdx.x;
    s[threadIdx.x] = (i < N) ? cnt[i] : 0;
    __syncthreads();
    for (int off = BS / 2; off > 0; off >>= 1) {
        if (threadIdx.x < off) s[threadIdx.x] += s[threadIdx.x + off];
        __syncthreads();
    }
    if (threadIdx.x == 0) bsum[blockIdx.x] = s[0];
}

// single block scans the (<=512) block sums, in-place exclusive
__global__ __launch_bounds__(512) void k_scan2(int* bsum, int nb) {
    __shared__ int s[512];
    int t = threadIdx.x;
    int v = (t < nb) ? bsum[t] : 0;
    s[t] = v;
    __syncthreads();
    for (int off = 1; off < 512; off <<= 1) {
        int u = (t >= off) ? s[t - off] : 0;
        __syncthreads();
        s[t] += u;
        __syncthreads();
    }
    if (t < nb) bsum[t] = s[t] - v;   // exclusive of self
}

__global__ __launch_bounds__(BS) void k_scan3(const int* __restrict__ cnt, const int* __restrict__ boff,
                                              int* __restrict__ row_ptr, int N) {
    __shared__ int s[BS];
    int t = threadIdx.x;
    int i = blockIdx.x * BS + t;
    int v = (i < N) ? cnt[i] : 0;
    s[t] = v;
    __syncthreads();
    for (int off = 1; off < BS; off <<= 1) {
        int u = (t >= off) ? s[t - off] : 0;
        __syncthreads();
        s[t] += u;
        __syncthreads();
    }
    int base = boff[blockIdx.x];
    if (i < N) row_ptr[i] = base + s[t] - v;
    if (i == N - 1) row_ptr[N] = base + s[t];
}

// entries[pos] = {src, bits(dinv[src]*dinv[dst])}
__global__ __launch_bounds__(BS) void k_fill(const int* __restrict__ src, const int* __restrict__ dst,
                                             const int* __restrict__ row_ptr, int* __restrict__ fillpos,
                                             const float* __restrict__ dinv, uint2* __restrict__ entries,
                                             int E) {
    int e = blockIdx.x * BS + threadIdx.x;
    if (e >= E) return;
    int s = src[e], d = dst[e];
    int pos = row_ptr[d] + atomicAdd(&fillpos[d], 1);
    float w = dinv[s] * dinv[d];
    entries[pos] = make_uint2((unsigned)s, __float_as_uint(w));
}

// ---------------- dense transform: out[N,M] = H[N,K] @ W[K,M] (+bias)(+relu) ----------------
// W staged in LDS padded to M4 cols; each thread computes 1 row x 4 cols.
__global__ __launch_bounds__(BS) void k_gemm(const float* __restrict__ H, const float* __restrict__ Wg,
                                             const float* __restrict__ bias, float* __restrict__ out,
                                             int N, int K, int M, int M4,
                                             unsigned long long invCG, int relu) {
    extern __shared__ float Wl[];  // K * M4
    for (int kk = 0; kk < K; ++kk)
        for (int cc = threadIdx.x; cc < M4; cc += BS)
            Wl[kk * M4 + cc] = (cc < M) ? Wg[kk * M + cc] : 0.f;
    __syncthreads();

    int CG = M4 >> 2;                 // column groups of 4
    int t = blockIdx.x * BS + threadIdx.x;
    if (t >= N * CG) return;
    int i  = (int)(((unsigned long long)t * invCG) >> 40);
    int cg = t - i * CG;
    int c0 = cg << 2;

    const float* hp = H + (size_t)i * K;
    float4 acc = make_float4(0.f, 0.f, 0.f, 0.f);
    for (int k = 0; k < K; ++k) {
        float h = hp[k];                                  // wave-broadcast (same row across lanes)
        const float4 w = *(const float4*)&Wl[k * M4 + c0];
        acc.x = fmaf(h, w.x, acc.x);
        acc.y = fmaf(h, w.y, acc.y);
        acc.z = fmaf(h, w.z, acc.z);
        acc.w = fmaf(h, w.w, acc.w);
    }
    float a[4] = {acc.x, acc.y, acc.z, acc.w};
    float* op = out + (size_t)i * M + c0;
    int rem = M - c0;
    #pragma unroll
    for (int j = 0; j < 4; ++j) {
        if (j < rem) {
            float v = a[j] + (bias ? bias[c0 + j] : 0.f);
            if (relu) v = fmaxf(v, 0.f);
            op[j] = v;
        }
    }
}

// ---------------- normalized aggregation: out = D^-1/2 (A+I) D^-1/2 @ T (+bias)(+relu) ----------------
// one thread per output element (node i, feature c); lanes cover consecutive c.
__global__ __launch_bounds__(BS) void k_agg(const float* __restrict__ T, float* __restrict__ out,
                                            const int* __restrict__ row_ptr, const uint2* __restrict__ entries,
                                            const float* __restrict__ dinv, const float* __restrict__ bias,
                                            int N, int M, unsigned long long invM, int relu) {
    int idx = blockIdx.x * BS + threadIdx.x;
    if (idx >= N * M) return;
    int i = (int)(((unsigned long long)idx * invM) >> 40);
    int c = idx - i * M;

    float di = dinv[i];
    float acc = di * di * T[idx];                   // self-loop, weight dinv[i]^2
    int e0 = row_ptr[i], e1 = row_ptr[i + 1];
    for (int e = e0; e < e1; ++e) {
        uint2 ent = entries[e];                     // wave-broadcast per node
        acc = fmaf(__uint_as_float(ent.y), T[ent.x * M + c], acc);
    }
    if (bias) acc += bias[c];
    if (relu) acc = fmaxf(acc, 0.f);
    out[idx] = acc;
}

// ---------------- driver ----------------

extern "C" void kernel_launch(void* const* d_in, const int* in_sizes, int n_in,
                              void* d_out, int out_size, void* d_ws, size_t ws_size,
                              hipStream_t stream) {
    const float* x  = (const float*)d_in[0];
    const float* W1 = (const float*)d_in[1];
    const float* b1 = (const float*)d_in[2];
    const float* W2 = (const float*)d_in[3];
    const float* b2 = (const float*)d_in[4];
    const float* W3 = (const float*)d_in[5];
    const float* b3 = (const float*)d_in[6];
    const float* W4 = (const float*)d_in[7];
    const float* b4 = (const float*)d_in[8];
    const int* edge_index = (const int*)d_in[9];

    const int N = in_sizes[0] / 88;
    const int E = in_sizes[9] / 2;
    const int* src = edge_index;
    const int* dst = edge_index + E;

    // workspace carve (256B aligned)
    char* p = (char*)d_ws;
    auto carve = [&](size_t bytes) { void* r = p; p += (bytes + 255) & ~(size_t)255; return r; };
    int*   cnt     = (int*)  carve((size_t)N * 4);
    float* dinv    = (float*)carve((size_t)N * 4);
    int*   row_ptr = (int*)  carve((size_t)(N + 1) * 4);
    int*   fillpos = (int*)  carve((size_t)N * 4);
    int*   bsum    = (int*)  carve(4096);
    uint2* entries = (uint2*)carve((size_t)E * 8);
    float* bufA    = (float*)carve((size_t)N * 88 * 4);
    float* bufB    = (float*)carve((size_t)N * 88 * 4);

    int gN = (N + BS - 1) / BS;
    int gE = (E + BS - 1) / BS;

    // CSR build
    k_zero2<<<gN, BS, 0, stream>>>(cnt, fillpos, N);
    k_hist <<<gE, BS, 0, stream>>>(dst, cnt, E);
    k_dinv <<<gN, BS, 0, stream>>>(cnt, dinv, N);
    int nb = gN;   // = 391 for N=100000, fits in one 512-thread scan block
    k_scan1<<<nb, BS, 0, stream>>>(cnt, bsum, N);
    k_scan2<<<1, 512, 0, stream>>>(bsum, nb);
    k_scan3<<<nb, BS, 0, stream>>>(cnt, bsum, row_ptr, N);
    k_fill <<<gE, BS, 0, stream>>>(src, dst, row_ptr, fillpos, dinv, entries, E);

    auto launch_gemm = [&](const float* Hin, const float* Wg, const float* bias,
                           float* out, int K, int M, int relu) {
        int M4 = (M + 3) & ~3;
        int CG = M4 >> 2;
        unsigned long long invCG = ((1ull << 40) + CG - 1) / CG;
        int total = N * CG;
        size_t lds = (size_t)K * M4 * 4;
        k_gemm<<<(total + BS - 1) / BS, BS, lds, stream>>>(Hin, Wg, bias, out, N, K, M, M4, invCG, relu);
    };
    auto launch_agg = [&](const float* T, float* out, const float* bias, int M, int relu) {
        unsigned long long invM = ((1ull << 40) + M - 1) / M;
        int total = N * M;
        k_agg<<<(total + BS - 1) / BS, BS, 0, stream>>>(T, out, row_ptr, entries, dinv, bias, N, M, invM, relu);
    };

    // Layer 1 (88->65): transform then aggregate (agg at 65), bias+relu in agg
    launch_gemm(x, W1, nullptr, bufA, 88, 65, 0);
    launch_agg(bufA, bufB, b1, 65, 1);
    // Layer 2 (65->50): transform then aggregate (agg at 50), bias in agg
    launch_gemm(bufB, W2, nullptr, bufA, 65, 50, 0);
    launch_agg(bufA, bufB, b2, 50, 0);
    // Layer 3 (50->65): aggregate first (agg at 50), then transform + bias + relu
    launch_agg(bufB, bufA, nullptr, 50, 0);
    launch_gemm(bufA, W3, b3, bufB, 50, 65, 1);
    // Layer 4 (65->88): aggregate first (agg at 65), then transform + bias
    launch_agg(bufB, bufA, nullptr, 65, 0);
    launch_gemm(bufA, W4, b4, (float*)d_out, 65, 88, 0);
}

// Round 2
// 730.664 us; speedup vs baseline: 1.8089x; 1.8089x over previous
//
#include <hip/hip_runtime.h>

#define BS 256

// ---------------- CSR build ----------------

__global__ __launch_bounds__(BS) void k_zero2(int* a, int* b, int n) {
    int i = blockIdx.x * BS + threadIdx.x;
    if (i < n) { a[i] = 0; b[i] = 0; }
}

__global__ __launch_bounds__(BS) void k_hist(const int* __restrict__ dst, int* __restrict__ cnt, int E) {
    int e = blockIdx.x * BS + threadIdx.x;
    if (e < E) atomicAdd(&cnt[dst[e]], 1);
}

__global__ __launch_bounds__(BS) void k_dinv(const int* __restrict__ cnt, float* __restrict__ dinv, int N) {
    int i = blockIdx.x * BS + threadIdx.x;
    if (i < N) dinv[i] = rsqrtf((float)(cnt[i] + 1));   // +1 = self-loop
}

__global__ __launch_bounds__(BS) void k_scan1(const int* __restrict__ cnt, int* __restrict__ bsum, int N) {
    __shared__ int s[BS];
    int i = blockIdx.x * BS + threadIdx.x;
    s[threadIdx.x] = (i < N) ? cnt[i] : 0;
    __syncthreads();
    for (int off = BS / 2; off > 0; off >>= 1) {
        if (threadIdx.x < off) s[threadIdx.x] += s[threadIdx.x + off];
        __syncthreads();
    }
    if (threadIdx.x == 0) bsum[blockIdx.x] = s[0];
}

__global__ __launch_bounds__(512) void k_scan2(int* bsum, int nb) {
    __shared__ int s[512];
    int t = threadIdx.x;
    int v = (t < nb) ? bsum[t] : 0;
    s[t] = v;
    __syncthreads();
    for (int off = 1; off < 512; off <<= 1) {
        int u = (t >= off) ? s[t - off] : 0;
        __syncthreads();
        s[t] += u;
        __syncthreads();
    }
    if (t < nb) bsum[t] = s[t] - v;   // exclusive of self
}

__global__ __launch_bounds__(BS) void k_scan3(const int* __restrict__ cnt, const int* __restrict__ boff,
                                              int* __restrict__ row_ptr, int N) {
    __shared__ int s[BS];
    int t = threadIdx.x;
    int i = blockIdx.x * BS + t;
    int v = (i < N) ? cnt[i] : 0;
    s[t] = v;
    __syncthreads();
    for (int off = 1; off < BS; off <<= 1) {
        int u = (t >= off) ? s[t - off] : 0;
        __syncthreads();
        s[t] += u;
        __syncthreads();
    }
    int base = boff[blockIdx.x];
    if (i < N) row_ptr[i] = base + s[t] - v;
    if (i == N - 1) row_ptr[N] = base + s[t];
}

__global__ __launch_bounds__(BS) void k_fill(const int* __restrict__ src, const int* __restrict__ dst,
                                             const int* __restrict__ row_ptr, int* __restrict__ fillpos,
                                             const float* __restrict__ dinv, uint2* __restrict__ entries,
                                             int E) {
    int e = blockIdx.x * BS + threadIdx.x;
    if (e >= E) return;
    int s = src[e], d = dst[e];
    int pos = row_ptr[d] + atomicAdd(&fillpos[d], 1);
    float w = dinv[s] * dinv[d];
    entries[pos] = make_uint2((unsigned)s, __float_as_uint(w));
}

// ---------------- dense transform ----------------
// out[N, LDOUT(pad0)] = H[N, LDIN] @ W[K, M] (+bias)(+relu)
// Thread computes R rows x full M in registers. W reads are wave-uniform ->
// scalar-cache s_load; FMA = v_fma_f32 acc, s_w, v_h. No LDS at all.
template<int R, int K, int M, int LDIN, int LDOUT, bool BIAS, bool RELU>
__global__ __launch_bounds__(BS) void k_gemm(const float* __restrict__ H, const float* __restrict__ Wg,
                                             const float* __restrict__ bias, float* __restrict__ out, int N) {
    int tid = threadIdx.x;
    int base = blockIdx.x * (BS * R) + tid;

    int   row[R];
    bool  ok[R];
    const float* hp[R];
    #pragma unroll
    for (int r = 0; r < R; ++r) {
        row[r] = base + BS * r;
        ok[r]  = row[r] < N;
        int rr = ok[r] ? row[r] : (N - 1);          // clamp: safe loads, masked stores
        hp[r]  = H + (size_t)rr * LDIN;
    }

    float acc[R][M];
    #pragma unroll
    for (int r = 0; r < R; ++r)
        #pragma unroll
        for (int m = 0; m < M; ++m) acc[r][m] = 0.f;

    constexpr int K4 = K & ~3;
    for (int k = 0; k < K4; k += 4) {
        float h[R][4];
        #pragma unroll
        for (int r = 0; r < R; ++r) {
            float4 v = *(const float4*)(hp[r] + k);
            h[r][0] = v.x; h[r][1] = v.y; h[r][2] = v.z; h[r][3] = v.w;
        }
        #pragma unroll
        for (int j = 0; j < 4; ++j) {
            const float* wrow = Wg + (size_t)(k + j) * M;
            #pragma unroll
            for (int m = 0; m < M; ++m) {
                float w = wrow[m];                  // uniform -> s_load
                #pragma unroll
                for (int r = 0; r < R; ++r) acc[r][m] = fmaf(h[r][j], w, acc[r][m]);
            }
        }
    }
    #pragma unroll
    for (int k = K4; k < K; ++k) {
        float h[R];
        #pragma unroll
        for (int r = 0; r < R; ++r) h[r] = hp[r][k];
        const float* wrow = Wg + (size_t)k * M;
        #pragma unroll
        for (int m = 0; m < M; ++m) {
            float w = wrow[m];
            #pragma unroll
            for (int r = 0; r < R; ++r) acc[r][m] = fmaf(h[r], w, acc[r][m]);
        }
    }

    #pragma unroll
    for (int r = 0; r < R; ++r) {
        if (!ok[r]) continue;
        float* op = out + (size_t)row[r] * LDOUT;
        #pragma unroll
        for (int g = 0; g < LDOUT / 4; ++g) {
            float4 v;
            float* vp = &v.x;
            #pragma unroll
            for (int j = 0; j < 4; ++j) {
                int m = g * 4 + j;
                float x = (m < M) ? acc[r][m] : 0.f;
                if (BIAS && m < M) x += bias[m];
                if (RELU) x = fmaxf(x, 0.f);
                vp[j] = x;
            }
            *(float4*)(op + g * 4) = v;
        }
    }
}

// ---------------- normalized aggregation ----------------
// out[i,:] = dinv_i^2*T[i,:] + sum_e w_e * T[src_e,:]  (+bias)(+relu)
// thread = (node i, 4-feature group); float4 gathers; rows padded to M4 (pad==0).
template<int M, int M4, bool BIAS, bool RELU>
__global__ __launch_bounds__(BS) void k_agg(const float* __restrict__ T, float* __restrict__ out,
                                            const int* __restrict__ row_ptr, const uint2* __restrict__ entries,
                                            const float* __restrict__ dinv, const float* __restrict__ bias,
                                            int N) {
    constexpr int CG = M4 / 4;
    int idx = blockIdx.x * BS + threadIdx.x;
    if (idx >= N * CG) return;
    int i  = idx / CG;                // const divisor -> magic mul
    int cg = idx - i * CG;
    int c0 = cg * 4;

    float di = dinv[i];
    float4 t0 = *(const float4*)(T + (size_t)i * M4 + c0);
    float w0 = di * di;
    float4 acc0 = make_float4(w0 * t0.x, w0 * t0.y, w0 * t0.z, w0 * t0.w);
    float4 acc1 = make_float4(0.f, 0.f, 0.f, 0.f);

    int e0 = row_ptr[i], e1 = row_ptr[i + 1];
    int e = e0;
    for (; e + 1 < e1; e += 2) {
        uint2 ea = entries[e];
        uint2 eb = entries[e + 1];
        float4 ta = *(const float4*)(T + (size_t)ea.x * M4 + c0);
        float4 tb = *(const float4*)(T + (size_t)eb.x * M4 + c0);
        float wa = __uint_as_float(ea.y);
        float wb = __uint_as_float(eb.y);
        acc0.x = fmaf(wa, ta.x, acc0.x); acc0.y = fmaf(wa, ta.y, acc0.y);
        acc0.z = fmaf(wa, ta.z, acc0.z); acc0.w = fmaf(wa, ta.w, acc0.w);
        acc1.x = fmaf(wb, tb.x, acc1.x); acc1.y = fmaf(wb, tb.y, acc1.y);
        acc1.z = fmaf(wb, tb.z, acc1.z); acc1.w = fmaf(wb, tb.w, acc1.w);
    }
    if (e < e1) {
        uint2 ea = entries[e];
        float4 ta = *(const float4*)(T + (size_t)ea.x * M4 + c0);
        float wa = __uint_as_float(ea.y);
        acc0.x = fmaf(wa, ta.x, acc0.x); acc0.y = fmaf(wa, ta.y, acc0.y);
        acc0.z = fmaf(wa, ta.z, acc0.z); acc0.w = fmaf(wa, ta.w, acc0.w);
    }
    acc0.x += acc1.x; acc0.y += acc1.y; acc0.z += acc1.z; acc0.w += acc1.w;

    float* vp = &acc0.x;
    #pragma unroll
    for (int j = 0; j < 4; ++j) {
        if (BIAS && (c0 + j) < M) vp[j] += bias[c0 + j];
        if (RELU) vp[j] = fmaxf(vp[j], 0.f);
    }
    *(float4*)(out + (size_t)i * M4 + c0) = acc0;
}

// ---------------- driver ----------------

extern "C" void kernel_launch(void* const* d_in, const int* in_sizes, int n_in,
                              void* d_out, int out_size, void* d_ws, size_t ws_size,
                              hipStream_t stream) {
    const float* x  = (const float*)d_in[0];
    const float* W1 = (const float*)d_in[1];
    const float* b1 = (const float*)d_in[2];
    const float* W2 = (const float*)d_in[3];
    const float* b2 = (const float*)d_in[4];
    const float* W3 = (const float*)d_in[5];
    const float* b3 = (const float*)d_in[6];
    const float* W4 = (const float*)d_in[7];
    const float* b4 = (const float*)d_in[8];
    const int* edge_index = (const int*)d_in[9];

    const int N = in_sizes[0] / 88;
    const int E = in_sizes[9] / 2;
    const int* src = edge_index;
    const int* dst = edge_index + E;

    char* p = (char*)d_ws;
    auto carve = [&](size_t bytes) { void* r = p; p += (bytes + 255) & ~(size_t)255; return r; };
    int*   cnt     = (int*)  carve((size_t)N * 4);
    float* dinv    = (float*)carve((size_t)N * 4);
    int*   row_ptr = (int*)  carve((size_t)(N + 1) * 4);
    int*   fillpos = (int*)  carve((size_t)N * 4);
    int*   bsum    = (int*)  carve(4096);
    uint2* entries = (uint2*)carve((size_t)E * 8);
    float* bufA    = (float*)carve((size_t)N * 68 * 4);
    float* bufB    = (float*)carve((size_t)N * 68 * 4);

    int gN = (N + BS - 1) / BS;
    int gE = (E + BS - 1) / BS;

    k_zero2<<<gN, BS, 0, stream>>>(cnt, fillpos, N);
    k_hist <<<gE, BS, 0, stream>>>(dst, cnt, E);
    k_dinv <<<gN, BS, 0, stream>>>(cnt, dinv, N);
    int nb = gN;
    k_scan1<<<nb, BS, 0, stream>>>(cnt, bsum, N);
    k_scan2<<<1, 512, 0, stream>>>(bsum, nb);
    k_scan3<<<nb, BS, 0, stream>>>(cnt, bsum, row_ptr, N);
    k_fill <<<gE, BS, 0, stream>>>(src, dst, row_ptr, fillpos, dinv, entries, E);

    auto gemm_grid = [&](int R) { return (N + BS * R - 1) / (BS * R); };
    auto agg_grid  = [&](int CG) { return (N * CG + BS - 1) / BS; };

    // L1: gemm 88->65 (ld 88 -> 68), then agg@65 +b1 +relu
    k_gemm<2, 88, 65, 88, 68, false, false><<<gemm_grid(2), BS, 0, stream>>>(x, W1, nullptr, bufA, N);
    k_agg<65, 68, true, true><<<agg_grid(17), BS, 0, stream>>>(bufA, bufB, row_ptr, entries, dinv, b1, N);
    // L2: gemm 65->50 (ld 68 -> 52), then agg@50 +b2
    k_gemm<2, 65, 50, 68, 52, false, false><<<gemm_grid(2), BS, 0, stream>>>(bufB, W2, nullptr, bufA, N);
    k_agg<50, 52, true, false><<<agg_grid(13), BS, 0, stream>>>(bufA, bufB, row_ptr, entries, dinv, b2, N);
    // L3: agg@50 first, then gemm 50->65 (+b3 +relu), out ld 68
    k_agg<50, 52, false, false><<<agg_grid(13), BS, 0, stream>>>(bufB, bufA, row_ptr, entries, dinv, nullptr, N);
    k_gemm<2, 50, 65, 52, 68, true, true><<<gemm_grid(2), BS, 0, stream>>>(bufA, W3, b3, bufB, N);
    // L4: agg@65 first, then gemm 65->88 (+b4) -> d_out (ld 88, no pad)
    k_agg<65, 68, false, false><<<agg_grid(17), BS, 0, stream>>>(bufB, bufA, row_ptr, entries, dinv, nullptr, N);
    k_gemm<1, 65, 88, 68, 88, true, false><<<gemm_grid(1), BS, 0, stream>>>(bufA, W4, b4, (float*)d_out, N);
}

// Round 3
// 617.802 us; speedup vs baseline: 2.1394x; 1.1827x over previous
//
#include <hip/hip_runtime.h>

#define BS 256

using half4 = __attribute__((ext_vector_type(4))) _Float16;

template<typename T>
__device__ __forceinline__ float4 load4(const T* p) {
    if constexpr (sizeof(T) == 4) {
        return *(const float4*)p;
    } else {
        half4 v = *(const half4*)p;
        return make_float4((float)v.x, (float)v.y, (float)v.z, (float)v.w);
    }
}
template<typename T>
__device__ __forceinline__ void store4(T* p, float4 v) {
    if constexpr (sizeof(T) == 4) {
        *(float4*)p = v;
    } else {
        half4 h = {(_Float16)v.x, (_Float16)v.y, (_Float16)v.z, (_Float16)v.w};
        *(half4*)p = h;
    }
}

// ---------------- CSR build ----------------

__global__ __launch_bounds__(BS) void k_zero2(int* a, int* b, int n) {
    int i = blockIdx.x * BS + threadIdx.x;
    if (i < n) { a[i] = 0; b[i] = 0; }
}

__global__ __launch_bounds__(BS) void k_hist(const int* __restrict__ dst, int* __restrict__ cnt, int E) {
    int e = blockIdx.x * BS + threadIdx.x;
    if (e < E) atomicAdd(&cnt[dst[e]], 1);
}

__global__ __launch_bounds__(BS) void k_dinv(const int* __restrict__ cnt, float* __restrict__ dinv, int N) {
    int i = blockIdx.x * BS + threadIdx.x;
    if (i < N) dinv[i] = rsqrtf((float)(cnt[i] + 1));   // +1 = self-loop
}

__global__ __launch_bounds__(BS) void k_scan1(const int* __restrict__ cnt, int* __restrict__ bsum, int N) {
    __shared__ int s[BS];
    int i = blockIdx.x * BS + threadIdx.x;
    s[threadIdx.x] = (i < N) ? cnt[i] : 0;
    __syncthreads();
    for (int off = BS / 2; off > 0; off >>= 1) {
        if (threadIdx.x < off) s[threadIdx.x] += s[threadIdx.x + off];
        __syncthreads();
    }
    if (threadIdx.x == 0) bsum[blockIdx.x] = s[0];
}

__global__ __launch_bounds__(512) void k_scan2(int* bsum, int nb) {
    __shared__ int s[512];
    int t = threadIdx.x;
    int v = (t < nb) ? bsum[t] : 0;
    s[t] = v;
    __syncthreads();
    for (int off = 1; off < 512; off <<= 1) {
        int u = (t >= off) ? s[t - off] : 0;
        __syncthreads();
        s[t] += u;
        __syncthreads();
    }
    if (t < nb) bsum[t] = s[t] - v;   // exclusive of self
}

__global__ __launch_bounds__(BS) void k_scan3(const int* __restrict__ cnt, const int* __restrict__ boff,
                                              int* __restrict__ row_ptr, int N) {
    __shared__ int s[BS];
    int t = threadIdx.x;
    int i = blockIdx.x * BS + t;
    int v = (i < N) ? cnt[i] : 0;
    s[t] = v;
    __syncthreads();
    for (int off = 1; off < BS; off <<= 1) {
        int u = (t >= off) ? s[t - off] : 0;
        __syncthreads();
        s[t] += u;
        __syncthreads();
    }
    int base = boff[blockIdx.x];
    if (i < N) row_ptr[i] = base + s[t] - v;
    if (i == N - 1) row_ptr[N] = base + s[t];
}

__global__ __launch_bounds__(BS) void k_fill(const int* __restrict__ src, const int* __restrict__ dst,
                                             const int* __restrict__ row_ptr, int* __restrict__ fillpos,
                                             const float* __restrict__ dinv, uint2* __restrict__ entries,
                                             int E) {
    int e = blockIdx.x * BS + threadIdx.x;
    if (e >= E) return;
    int s = src[e], d = dst[e];
    int pos = row_ptr[d] + atomicAdd(&fillpos[d], 1);
    float w = dinv[s] * dinv[d];
    entries[pos] = make_uint2((unsigned)s, __float_as_uint(w));
}

// ---------------- dense transform ----------------
// out[N, LDOUT(pad0)] = H[N, LDIN] @ W[K, M] (+bias)(+relu); W via scalar loads.
template<int R, int K, int M, int LDIN, int LDOUT, bool BIAS, bool RELU, typename TOUT>
__global__ __launch_bounds__(BS) void k_gemm(const float* __restrict__ H, const float* __restrict__ Wg,
                                             const float* __restrict__ bias, TOUT* __restrict__ out, int N) {
    int tid = threadIdx.x;
    int base = blockIdx.x * (BS * R) + tid;

    int   row[R];
    bool  ok[R];
    const float* hp[R];
    #pragma unroll
    for (int r = 0; r < R; ++r) {
        row[r] = base + BS * r;
        ok[r]  = row[r] < N;
        int rr = ok[r] ? row[r] : (N - 1);          // clamp: safe loads, masked stores
        hp[r]  = H + (size_t)rr * LDIN;
    }

    float acc[R][M];
    #pragma unroll
    for (int r = 0; r < R; ++r)
        #pragma unroll
        for (int m = 0; m < M; ++m) acc[r][m] = 0.f;

    constexpr int K4 = K & ~3;
    for (int k = 0; k < K4; k += 4) {
        float h[R][4];
        #pragma unroll
        for (int r = 0; r < R; ++r) {
            float4 v = *(const float4*)(hp[r] + k);
            h[r][0] = v.x; h[r][1] = v.y; h[r][2] = v.z; h[r][3] = v.w;
        }
        #pragma unroll
        for (int j = 0; j < 4; ++j) {
            const float* wrow = Wg + (size_t)(k + j) * M;
            #pragma unroll
            for (int m = 0; m < M; ++m) {
                float w = wrow[m];                  // uniform -> s_load
                #pragma unroll
                for (int r = 0; r < R; ++r) acc[r][m] = fmaf(h[r][j], w, acc[r][m]);
            }
        }
    }
    #pragma unroll
    for (int k = K4; k < K; ++k) {
        float h[R];
        #pragma unroll
        for (int r = 0; r < R; ++r) h[r] = hp[r][k];
        const float* wrow = Wg + (size_t)k * M;
        #pragma unroll
        for (int m = 0; m < M; ++m) {
            float w = wrow[m];
            #pragma unroll
            for (int r = 0; r < R; ++r) acc[r][m] = fmaf(h[r], w, acc[r][m]);
        }
    }

    #pragma unroll
    for (int r = 0; r < R; ++r) {
        if (!ok[r]) continue;
        TOUT* op = out + (size_t)row[r] * LDOUT;
        #pragma unroll
        for (int g = 0; g < LDOUT / 4; ++g) {
            float4 v;
            float* vp = &v.x;
            #pragma unroll
            for (int j = 0; j < 4; ++j) {
                int m = g * 4 + j;
                float x = (m < M) ? acc[r][m] : 0.f;
                if (BIAS && m < M) x += bias[m];
                if (RELU) x = fmaxf(x, 0.f);
                vp[j] = x;
            }
            store4(op + g * 4, v);
        }
    }
}

// ---------------- normalized aggregation ----------------
// out[i,:] = dinv_i^2*T[i,:] + sum_e w_e * T[src_e,:]  (+bias)(+relu)
template<typename TIN, typename TOUT, int M, int M4, bool BIAS, bool RELU>
__global__ __launch_bounds__(BS) void k_agg(const TIN* __restrict__ T, TOUT* __restrict__ out,
                                            const int* __restrict__ row_ptr, const uint2* __restrict__ entries,
                                            const float* __restrict__ dinv, const float* __restrict__ bias,
                                            int N) {
    constexpr int CG = M4 / 4;
    int idx = blockIdx.x * BS + threadIdx.x;
    if (idx >= N * CG) return;
    int i  = idx / CG;                // const divisor -> magic mul
    int cg = idx - i * CG;
    int c0 = cg * 4;

    float di = dinv[i];
    float4 t0 = load4(T + (size_t)i * M4 + c0);
    float w0 = di * di;
    float4 acc0 = make_float4(w0 * t0.x, w0 * t0.y, w0 * t0.z, w0 * t0.w);
    float4 acc1 = make_float4(0.f, 0.f, 0.f, 0.f);

    int e0 = row_ptr[i], e1 = row_ptr[i + 1];
    int e = e0;
    for (; e + 3 < e1; e += 4) {
        uint2 ea = entries[e];
        uint2 eb = entries[e + 1];
        uint2 ec = entries[e + 2];
        uint2 ed = entries[e + 3];
        float4 ta = load4(T + (size_t)ea.x * M4 + c0);
        float4 tb = load4(T + (size_t)eb.x * M4 + c0);
        float4 tc = load4(T + (size_t)ec.x * M4 + c0);
        float4 td = load4(T + (size_t)ed.x * M4 + c0);
        float wa = __uint_as_float(ea.y), wb = __uint_as_float(eb.y);
        float wc = __uint_as_float(ec.y), wd = __uint_as_float(ed.y);
        acc0.x = fmaf(wa, ta.x, acc0.x); acc0.y = fmaf(wa, ta.y, acc0.y);
        acc0.z = fmaf(wa, ta.z, acc0.z); acc0.w = fmaf(wa, ta.w, acc0.w);
        acc1.x = fmaf(wb, tb.x, acc1.x); acc1.y = fmaf(wb, tb.y, acc1.y);
        acc1.z = fmaf(wb, tb.z, acc1.z); acc1.w = fmaf(wb, tb.w, acc1.w);
        acc0.x = fmaf(wc, tc.x, acc0.x); acc0.y = fmaf(wc, tc.y, acc0.y);
        acc0.z = fmaf(wc, tc.z, acc0.z); acc0.w = fmaf(wc, tc.w, acc0.w);
        acc1.x = fmaf(wd, td.x, acc1.x); acc1.y = fmaf(wd, td.y, acc1.y);
        acc1.z = fmaf(wd, td.z, acc1.z); acc1.w = fmaf(wd, td.w, acc1.w);
    }
    for (; e < e1; ++e) {
        uint2 ea = entries[e];
        float4 ta = load4(T + (size_t)ea.x * M4 + c0);
        float wa = __uint_as_float(ea.y);
        acc0.x = fmaf(wa, ta.x, acc0.x); acc0.y = fmaf(wa, ta.y, acc0.y);
        acc0.z = fmaf(wa, ta.z, acc0.z); acc0.w = fmaf(wa, ta.w, acc0.w);
    }
    acc0.x += acc1.x; acc0.y += acc1.y; acc0.z += acc1.z; acc0.w += acc1.w;

    float* vp = &acc0.x;
    #pragma unroll
    for (int j = 0; j < 4; ++j) {
        if (BIAS && (c0 + j) < M) vp[j] += bias[c0 + j];
        if (RELU) vp[j] = fmaxf(vp[j], 0.f);
    }
    store4(out + (size_t)i * M4 + c0, acc0);
}

// ---------------- driver ----------------

extern "C" void kernel_launch(void* const* d_in, const int* in_sizes, int n_in,
                              void* d_out, int out_size, void* d_ws, size_t ws_size,
                              hipStream_t stream) {
    const float* x  = (const float*)d_in[0];
    const float* W1 = (const float*)d_in[1];
    const float* b1 = (const float*)d_in[2];
    const float* W2 = (const float*)d_in[3];
    const float* b2 = (const float*)d_in[4];
    const float* W3 = (const float*)d_in[5];
    const float* b3 = (const float*)d_in[6];
    const float* W4 = (const float*)d_in[7];
    const float* b4 = (const float*)d_in[8];
    const int* edge_index = (const int*)d_in[9];

    const int N = in_sizes[0] / 88;
    const int E = in_sizes[9] / 2;
    const int* src = edge_index;
    const int* dst = edge_index + E;

    char* p = (char*)d_ws;
    auto carve = [&](size_t bytes) { void* r = p; p += (bytes + 255) & ~(size_t)255; return r; };
    int*   cnt     = (int*)  carve((size_t)N * 4);
    float* dinv    = (float*)carve((size_t)N * 4);
    int*   row_ptr = (int*)  carve((size_t)(N + 1) * 4);
    int*   fillpos = (int*)  carve((size_t)N * 4);
    int*   bsum    = (int*)  carve(4096);
    uint2* entries = (uint2*)carve((size_t)E * 8);
    _Float16* hA   = (_Float16*)carve((size_t)N * 68 * 2);
    _Float16* hB   = (_Float16*)carve((size_t)N * 68 * 2);
    float*    fA   = (float*)   carve((size_t)N * 68 * 4);

    int gN = (N + BS - 1) / BS;
    int gE = (E + BS - 1) / BS;

    k_zero2<<<gN, BS, 0, stream>>>(cnt, fillpos, N);
    k_hist <<<gE, BS, 0, stream>>>(dst, cnt, E);
    k_dinv <<<gN, BS, 0, stream>>>(cnt, dinv, N);
    int nb = gN;
    k_scan1<<<nb, BS, 0, stream>>>(cnt, bsum, N);
    k_scan2<<<1, 512, 0, stream>>>(bsum, nb);
    k_scan3<<<nb, BS, 0, stream>>>(cnt, bsum, row_ptr, N);
    k_fill <<<gE, BS, 0, stream>>>(src, dst, row_ptr, fillpos, dinv, entries, E);

    auto gemm_grid = [&](int R) { return (N + BS * R - 1) / (BS * R); };
    auto agg_grid  = [&](int CG) { return (N * CG + BS - 1) / BS; };

    // G1: x(f32,88) @ W1 -> hA(half,68)
    k_gemm<2, 88, 65, 88, 68, false, false, _Float16><<<gemm_grid(2), BS, 0, stream>>>(x, W1, nullptr, hA, N);
    // A1: agg(hA) +b1 +relu -> fA(f32,68)
    k_agg<_Float16, float, 65, 68, true, true><<<agg_grid(17), BS, 0, stream>>>(hA, fA, row_ptr, entries, dinv, b1, N);
    // G2: fA(68) @ W2 -> hB(half,52)
    k_gemm<2, 65, 50, 68, 52, false, false, _Float16><<<gemm_grid(2), BS, 0, stream>>>(fA, W2, nullptr, hB, N);
    // A2: agg(hB) +b2 -> hA(half,52)
    k_agg<_Float16, _Float16, 50, 52, true, false><<<agg_grid(13), BS, 0, stream>>>(hB, hA, row_ptr, entries, dinv, b2, N);
    // A3: agg(hA) -> fA(f32,52)
    k_agg<_Float16, float, 50, 52, false, false><<<agg_grid(13), BS, 0, stream>>>(hA, fA, row_ptr, entries, dinv, nullptr, N);
    // G3: fA(52) @ W3 +b3 +relu -> hB(half,68)
    k_gemm<2, 50, 65, 52, 68, true, true, _Float16><<<gemm_grid(2), BS, 0, stream>>>(fA, W3, b3, hB, N);
    // A4: agg(hB) -> fA(f32,68)
    k_agg<_Float16, float, 65, 68, false, false><<<agg_grid(17), BS, 0, stream>>>(hB, fA, row_ptr, entries, dinv, nullptr, N);
    // G4: fA(68) @ W4 +b4 -> d_out(f32,88)
    k_gemm<1, 65, 88, 68, 88, true, false, float><<<gemm_grid(1), BS, 0, stream>>>(fA, W4, b4, (float*)d_out, N);
}